// Round 8
// baseline (761.281 us; speedup 1.0000x reference)
//
#include <hip/hip_runtime.h>
#include <hip/hip_bf16.h>
#include <cstdint>

// GaussMemoryStep: everything reduced to bf16 MFMA GEMMs.
// F[n,j<256]=cos(2pi(j+1)n/V), F[n,256+j]=-sin(2pi(j+1)n/V);  irfft == @ (2/V)F^T.

typedef unsigned short u16;
typedef short short8 __attribute__((ext_vector_type(8)));
typedef float f32x4 __attribute__((ext_vector_type(4)));
typedef float f4 __attribute__((ext_vector_type(4)));

__device__ __forceinline__ u16 f2bf(float f) {
  union { float f; unsigned u; } v; v.f = f;
  unsigned u = v.u;
  u += 0x7fffu + ((u >> 16) & 1u);   // round-to-nearest-even
  return (u16)(u >> 16);
}

__device__ __forceinline__ void gload_lds16(const void* g, void* l) {
  __builtin_amdgcn_global_load_lds(
      (const __attribute__((address_space(1))) void*)g,
      (__attribute__((address_space(3))) void*)l, 16, 0, 0);
}

// ---------------------------------------------------------------------------
// G1: P[z] = x[:, z*4096:(z+1)*4096] @ Ft[:, z*4096:...]^T
// A fp32 [8192][8192], B bf16 [512][8192] ([N][K] row-major), P fp32 [2][8192][512].
// A goes GLOBAL -> REG -> MFMA-FRAG directly (no As LDS, no ds_write).
// LDS holds only Bs (2 x 8 KB).
// ROUND 8 FIX: BK=32 rows have only FOUR 8-u16 slots -> swizzle mask must be
// &3 (2 bits), not &7. Round-7's &7 XOR overflowed the row (read/write of
// k+32..k+56, wrong data for rows with row&4). Both sides now use
// slot ^ (row&3); closed over the 4-slot space, same involution write+read.
// vmcnt ledger per iter (order pinned):
//   entering iter t: A(t)x8 outstanding.
//   ISSUE_B(t+1)x2 -> 10;  CONVERT rv(t) [implicit wait drains A(t)];
//   ISSUE_A(t+1)x8 -> 10;  MFMA;  fence vmcnt(8) drains B(t+1), keeps A(t+1).
// ---------------------------------------------------------------------------
__global__ __launch_bounds__(256, 3)
void gemm_g1(const float* __restrict__ A, const u16* __restrict__ B,
             float* __restrict__ P)
{
  constexpr int NN = 512, KK = 8192, KC = 4096;
  constexpr int NT = KC / 32;   // 128 K-iterations per block, BK=32

  __shared__ u16 Bs[2][128 * 32] __attribute__((aligned(16)));

  const int tid  = threadIdx.x;
  const int wave = tid >> 6, lane = tid & 63;
  const int quad = lane >> 4, l15 = lane & 15;
  const int wm = wave >> 1, wn = wave & 1;

  // XCD-chunked bijective swizzle: xcd = lid%8 owns natural ids [xcd*64, xcd*64+64)
  const int lid = blockIdx.x;                 // 0..511
  const int nat = (lid & 7) * 64 + (lid >> 3);
  const int y = nat >> 3, rem = nat & 7;
  const int x = rem & 3, z = rem >> 2;        // y: M-panel, x: N-panel, z: K-chunk
  const int m0 = y * 128, n0 = x * 128, k00 = z * KC;

  // B staging: tile 128 rows x 32 u16 (64 B/row) = 8 KB -> 2 gload_lds.
  // Linear LDS: inst h, thread t -> byte h*4096 + t*16 ->
  //   row = h*64 + (t>>2), slot = t&3.  Source col pre-XOR'd with (row&3).
  const int brow4 = tid >> 2;                                   // 0..63
  const int bcol  = ((tid & 3) * 8) ^ ((brow4 & 3) * 8);        // u16; 2-bit mask
  const u16* Bp = B + (size_t)(n0 + brow4) * KK + k00 + bcol;
  const int bloff = tid * 16;                                   // byte, + h*4096

  // A fragment geometry: frag i -> row m0 + wm*64 + i*16 + l15, col quad*8 fp32
  const float* Ap = A + (size_t)(m0 + wm * 64 + l15) * KK + k00 + quad * 8;

  const int swzB = (l15 & 3) * 8;   // read-side XOR for Bs (u16 units, 2-bit)

  f4 rv[8];          // A prefetch: frag i -> rv[2i], rv[2i+1]
  short8 af[4];      // A fragments (converted)
  f32x4 acc[4][4] = {};

#define ISSUE_B(T, SLOT)                                             \
  _Pragma("unroll")                                                  \
  for (int h = 0; h < 2; ++h)                                        \
    gload_lds16(Bp + (size_t)h * 64 * KK + (size_t)(T) * 32,         \
                (char*)Bs[SLOT] + h * 4096 + bloff);
#define ISSUE_A(T)                                                   \
  _Pragma("unroll")                                                  \
  for (int i = 0; i < 4; ++i) {                                      \
    rv[2 * i]     = *(const f4*)(Ap + (size_t)i * 16 * KK + (size_t)(T) * 32);     \
    rv[2 * i + 1] = *(const f4*)(Ap + (size_t)i * 16 * KK + (size_t)(T) * 32 + 4); \
  }
#define CONVERT_A()                                                  \
  _Pragma("unroll")                                                  \
  for (int i = 0; i < 4; ++i) {                                      \
    union { u16 h[8]; short8 s; } pk;                                \
    _Pragma("unroll")                                                \
    for (int e = 0; e < 4; ++e) {                                    \
      pk.h[e]     = f2bf(rv[2 * i][e]);                              \
      pk.h[4 + e] = f2bf(rv[2 * i + 1][e]);                          \
    }                                                                \
    af[i] = pk.s;                                                    \
  }
#define G1_COMPUTE(CUR)                                                          \
  {                                                                              \
    short8 b[4];                                                                 \
    _Pragma("unroll")                                                            \
    for (int j = 0; j < 4; ++j)                                                  \
      b[j] = *(const short8*)&Bs[CUR][(wn * 64 + j * 16 + l15) * 32 +            \
                                      ((quad * 8) ^ swzB)];                      \
    _Pragma("unroll")                                                            \
    for (int i = 0; i < 4; ++i)                                                  \
      _Pragma("unroll")                                                          \
      for (int j = 0; j < 4; ++j)                                                \
        acc[i][j] = __builtin_amdgcn_mfma_f32_16x16x32_bf16(af[i], b[j], acc[i][j], 0, 0, 0); \
  }
#define SB() __builtin_amdgcn_sched_barrier(0)
#define FENCE_BAR()                                                  \
  asm volatile("s_waitcnt vmcnt(8)" ::: "memory");                   \
  __builtin_amdgcn_s_barrier();                                      \
  asm volatile("" ::: "memory");

  // prologue: B(0)x2 then A(0)x8 -> 10 outstanding; vmcnt(8) drains B(0),
  // keeps A(0)x8 = loop-entry invariant.
  ISSUE_B(0, 0);
  SB();
  ISSUE_A(0);
  SB();
  FENCE_BAR();

  for (int t = 0; t < NT; ++t) {
    const int tn = (t + 1 < NT) ? t + 1 : NT - 1;
    ISSUE_B(tn, (t + 1) & 1);
    SB();
    CONVERT_A();            // implicit wait drains A(t), keeps B(t+1)
    ISSUE_A(tn);
    SB();
    G1_COMPUTE(t & 1);
    FENCE_BAR();            // vmcnt(8): drains B(t+1), keeps A(t+1)
  }
#undef FENCE_BAR
#undef SB
#undef G1_COMPUTE
#undef CONVERT_A
#undef ISSUE_A
#undef ISSUE_B

  // epilogue: fp32 partials
  float* Pz = P + (size_t)z * (8192L * 512);
  #pragma unroll
  for (int i = 0; i < 4; ++i) {
    #pragma unroll
    for (int j = 0; j < 4; ++j) {
      const int rb = m0 + wm * 64 + i * 16 + quad * 4;
      const int cc = n0 + wn * 64 + j * 16 + l15;
      #pragma unroll
      for (int r = 0; r < 4; ++r)
        Pz[(size_t)(rb + r) * NN + cc] = acc[i][j][r];
    }
  }
}

// O = bf16(P[i] + P[i + half_f4])
__global__ void reduce_cast(const float* __restrict__ P, u16* __restrict__ O,
                            int half_f4) {
  const int i = blockIdx.x * 256 + threadIdx.x;
  const f4 a = ((const f4*)P)[i];
  const f4 b = ((const f4*)P)[i + half_f4];
  union { u16 h[4]; uint2 q; } pk;
  #pragma unroll
  for (int r = 0; r < 4; ++r) pk.h[r] = f2bf(a[r] + b[r]);
  ((uint2*)O)[i] = pk.q;
}

// ---------------------------------------------------------------------------
// Shared pipelined bf16 K-loop: BK=64, 2 LDS buffers,
// {stage(t+1) -> compute(t) -> vmcnt(0) -> barrier}, XOR swizzle both-sides
// ((row&7), valid: 8 slots per 64-u16 row).
// ---------------------------------------------------------------------------
__device__ __forceinline__ void kloop_p(
    const u16* __restrict__ Ab, const u16* __restrict__ Bb, int K,
    int m0, int n0, int kbeg, int kend, int tid,
    u16* As, u16* Bs, f32x4 (&acc)[4][4])
{
  const int wave = tid >> 6, lane = tid & 63;
  const int quad = lane >> 4, l15 = lane & 15;
  const int wm = wave >> 1, wn = wave & 1;
  const int swz8 = (l15 & 7) << 3;

  const int brow = tid >> 3;                                    // 0..31
  const int rswz = ((tid & 7) * 8) ^ ((brow & 7) << 3);         // u16
  const u16* Apg = Ab + (size_t)(m0 + brow) * K + rswz;
  const u16* Bpg = Bb + (size_t)(n0 + brow) * K + rswz;
  const int dof = tid * 16;                                     // byte

#define STG_P(K0, SLOT)                                                     \
  _Pragma("unroll")                                                         \
  for (int h = 0; h < 4; ++h) {                                             \
    gload_lds16(Apg + (size_t)h * 32 * K + (K0),                            \
                (char*)As + (SLOT) * 16384 + h * 4096 + dof);               \
    gload_lds16(Bpg + (size_t)h * 32 * K + (K0),                            \
                (char*)Bs + (SLOT) * 16384 + h * 4096 + dof);               \
  }

  STG_P(kbeg, 0);
  asm volatile("s_waitcnt vmcnt(0)" ::: "memory");
  __builtin_amdgcn_s_barrier();
  asm volatile("" ::: "memory");

  int buf = 0;
  for (int k0 = kbeg; k0 < kend; k0 += 64) {
    if (k0 + 64 < kend) STG_P(k0 + 64, buf ^ 1);
    #pragma unroll
    for (int ks = 0; ks < 2; ++ks) {
      short8 a[4], b[4];
      #pragma unroll
      for (int i = 0; i < 4; ++i)
        a[i] = *(const short8*)&As[buf * 8192 + (wm * 64 + i * 16 + l15) * 64 +
                                   ((ks * 32 + quad * 8) ^ swz8)];
      #pragma unroll
      for (int j = 0; j < 4; ++j)
        b[j] = *(const short8*)&Bs[buf * 8192 + (wn * 64 + j * 16 + l15) * 64 +
                                   ((ks * 32 + quad * 8) ^ swz8)];
      #pragma unroll
      for (int i = 0; i < 4; ++i)
        #pragma unroll
        for (int j = 0; j < 4; ++j)
          acc[i][j] = __builtin_amdgcn_mfma_f32_16x16x32_bf16(a[i], b[j], acc[i][j], 0, 0, 0);
    }
    asm volatile("s_waitcnt vmcnt(0)" ::: "memory");
    __builtin_amdgcn_s_barrier();
    asm volatile("" ::: "memory");
    buf ^= 1;
  }
#undef STG_P
}

// ---------------------------------------------------------------------------
// Merged Q/K/V/Wot: four M=8192,N=256,K=512 GEMMs as z-slices.
// ---------------------------------------------------------------------------
__global__ __launch_bounds__(256, 2)
void gemm_qkvw(const u16* __restrict__ Xri, const u16* __restrict__ Fm,
               const u16* __restrict__ qwb, const u16* __restrict__ kwb,
               const u16* __restrict__ vwb, const u16* __restrict__ owb,
               u16* __restrict__ Qb, u16* __restrict__ Kb,
               u16* __restrict__ Vt, u16* __restrict__ Wot)
{
  constexpr int N = 256, K = 512;
  __shared__ u16 As[2 * 128 * 64] __attribute__((aligned(16)));
  __shared__ u16 Bs[2 * 128 * 64] __attribute__((aligned(16)));

  const int tid  = threadIdx.x;
  const int wave = tid >> 6, lane = tid & 63;
  const int quad = lane >> 4, l15 = lane & 15;
  const int wm = wave >> 1, wn = wave & 1;
  const int m0 = blockIdx.y * 128, n0 = blockIdx.x * 128;
  const int z  = blockIdx.z;

  const u16* Ab = (z == 3) ? Fm : Xri;
  const u16* Bb = (z == 0) ? qwb : (z == 1) ? kwb : (z == 2) ? vwb : owb;
  const float alpha = (z == 3) ? (2.f / 8192.f) : 1.f;

  f32x4 acc[4][4] = {};
  kloop_p(Ab, Bb, K, m0, n0, 0, K, tid, As, Bs, acc);

  #pragma unroll
  for (int i = 0; i < 4; ++i) {
    #pragma unroll
    for (int j = 0; j < 4; ++j) {
      f32x4 v = acc[i][j];
      const int rb = m0 + wm * 64 + i * 16 + quad * 4;
      const int cc = n0 + wn * 64 + j * 16 + l15;
      if (z == 2) {
        const int bb = rb >> 11, ml = rb & 2047;
        union { u16 h[4]; uint2 q; } pk;
        #pragma unroll
        for (int r = 0; r < 4; ++r) pk.h[r] = f2bf(v[r]);
        *(uint2*)&Vt[((size_t)(bb << 8) + cc) * 2048 + ml] = pk.q;
      } else {
        u16* C = (z == 0) ? Qb : (z == 1) ? Kb : Wot;
        #pragma unroll
        for (int r = 0; r < 4; ++r)
          C[(size_t)(rb + r) * N + cc] = f2bf(v[r] * alpha);
      }
    }
  }
}

// ---------------------------------------------------------------------------
// G4: S[b] = (q k^T) .* decay-weight, upper-triangular blocks only.
// ---------------------------------------------------------------------------
__global__ __launch_bounds__(256, 2)
void gemm_g4(const u16* __restrict__ Qb, const u16* __restrict__ Kb,
             u16* __restrict__ S, const float* __restrict__ dl)
{
  if (blockIdx.x < blockIdx.y) return;
  constexpr int N = 2048, K = 256;
  __shared__ u16 As[2 * 128 * 64] __attribute__((aligned(16)));
  __shared__ u16 Bs[2 * 128 * 64] __attribute__((aligned(16)));

  const int tid  = threadIdx.x;
  const int wave = tid >> 6, lane = tid & 63;
  const int quad = lane >> 4, l15 = lane & 15;
  const int wm = wave >> 1, wn = wave & 1;
  const int m0 = blockIdx.y * 128, n0 = blockIdx.x * 128;
  const int z  = blockIdx.z;

  const u16* Ab = Qb + (size_t)z * 2048 * 256;
  const u16* Bb = Kb + (size_t)z * 2048 * 256;

  f32x4 acc[4][4] = {};
  kloop_p(Ab, Bb, K, m0, n0, 0, K, tid, As, Bs, acc);

  const float logit = *dl;
  const float dec = 1.f / (1.f + expf(-logit));
  const float dec_l2 = log2f(dec);
  u16* C = S + (size_t)z * 2048 * 2048;

  #pragma unroll
  for (int i = 0; i < 4; ++i) {
    #pragma unroll
    for (int j = 0; j < 4; ++j) {
      f32x4 v = acc[i][j];
      const int rb = m0 + wm * 64 + i * 16 + quad * 4;
      const int cc = n0 + wn * 64 + j * 16 + l15;
      #pragma unroll
      for (int r = 0; r < 4; ++r) {
        const int d = cc - (rb + r);            // s - t
        float w = (d > 0) ? exp2f(dec_l2 * (float)(d - 1)) : 0.f;
        C[(size_t)(rb + r) * N + cc] = f2bf(v[r] * w);
      }
    }
  }
}

// ---------------------------------------------------------------------------
// G5: R partials = S[b] @ Vt[b], trapezoidal K + split-K=2.
// ---------------------------------------------------------------------------
__global__ __launch_bounds__(256, 2)
void gemm_g5(const u16* __restrict__ S, const u16* __restrict__ Vt,
             float* __restrict__ P5)
{
  constexpr int N = 256, K = 2048;
  __shared__ u16 As[2 * 128 * 64] __attribute__((aligned(16)));
  __shared__ u16 Bs[2 * 128 * 64] __attribute__((aligned(16)));

  const int tid  = threadIdx.x;
  const int wave = tid >> 6, lane = tid & 63;
  const int quad = lane >> 4, l15 = lane & 15;
  const int wm = wave >> 1, wn = wave & 1;
  const int m0 = blockIdx.y * 128, n0 = blockIdx.x * 128;
  const int batch = blockIdx.z & 3, half = blockIdx.z >> 2;

  const u16* Ab = S  + (size_t)batch * 2048 * 2048;
  const u16* Bb = Vt + (size_t)batch * 256 * 2048;

  int kbeg = half * 1024;
  if (m0 > kbeg) kbeg = m0;          // S[t,s]==0 for s<=t
  const int kend = half * 1024 + 1024;

  f32x4 acc[4][4] = {};
  if (kbeg < kend)
    kloop_p(Ab, Bb, K, m0, n0, kbeg, kend, tid, As, Bs, acc);

  float* Pz = P5 + (size_t)half * (8192L * 256) + (size_t)batch * 2048 * 256;
  #pragma unroll
  for (int i = 0; i < 4; ++i) {
    #pragma unroll
    for (int j = 0; j < 4; ++j) {
      const int rb = m0 + wm * 64 + i * 16 + quad * 4;
      const int cc = n0 + wn * 64 + j * 16 + l15;
      #pragma unroll
      for (int r = 0; r < 4; ++r)
        Pz[(size_t)(rb + r) * N + cc] = acc[i][j][r];
    }
  }
}

// ---------------------------------------------------------------------------
// G6: out = (R @ Wot^T) * out_scale,  M=N=8192 K=256, fp32 out.
// ---------------------------------------------------------------------------
__global__ __launch_bounds__(256, 2)
void gemm_g6(const u16* __restrict__ R, const u16* __restrict__ Wot,
             float* __restrict__ out, const float* __restrict__ os)
{
  constexpr int N = 8192, K = 256;
  __shared__ u16 As[2 * 128 * 64] __attribute__((aligned(16)));
  __shared__ u16 Bs[2 * 128 * 64] __attribute__((aligned(16)));

  const int tid  = threadIdx.x;
  const int wave = tid >> 6, lane = tid & 63;
  const int quad = lane >> 4, l15 = lane & 15;
  const int wm = wave >> 1, wn = wave & 1;
  const int m0 = blockIdx.y * 128, n0 = blockIdx.x * 128;

  f32x4 acc[4][4] = {};
  kloop_p(R, Wot, K, m0, n0, 0, K, tid, As, Bs, acc);

  const float oscale = *os;
  #pragma unroll
  for (int i = 0; i < 4; ++i) {
    #pragma unroll
    for (int j = 0; j < 4; ++j) {
      const int rb = m0 + wm * 64 + i * 16 + quad * 4;
      const int cc = n0 + wn * 64 + j * 16 + l15;
      #pragma unroll
      for (int r = 0; r < 4; ++r)
        out[(size_t)(rb + r) * N + cc] = acc[i][j][r] * oscale;
    }
  }
}

// ---------------------------------------------------------------------------
// prep: genF_row + genF_col + cast_w4 merged into one launch.
// blocks [0,16384): Fm;  [16384,32768): Ft;  [32768,33280): weight casts.
// ---------------------------------------------------------------------------
__global__ void prep(u16* __restrict__ Fm, u16* __restrict__ Ft,
                     const float* __restrict__ qw, const float* __restrict__ kw,
                     const float* __restrict__ vw, const float* __restrict__ ow,
                     u16* __restrict__ qwb, u16* __restrict__ kwb,
                     u16* __restrict__ vwb, u16* __restrict__ owb)
{
  const int b = blockIdx.x;
  if (b < 16384) {
    int idx = b * 256 + threadIdx.x;          // Fm [8192][512], coalesced in j
    int n = idx >> 9, j = idx & 511;
    int k = (j & 255) + 1;
    int ph = (n * k) & 8191;
    float ang = (float)ph * 7.66990393942820795e-4f;  // 2*pi/8192
    float s, c; sincosf(ang, &s, &c);
    Fm[idx] = f2bf(j < 256 ? c : -s);
  } else if (b < 32768) {
    int idx = (b - 16384) * 256 + threadIdx.x; // Ft [512][8192], coalesced in n
    int j = idx >> 13, n = idx & 8191;
    int k = (j & 255) + 1;
    int ph = (n * k) & 8191;
    float ang = (float)ph * 7.66990393942820795e-4f;
    float s, c; sincosf(ang, &s, &c);
    Ft[idx] = f2bf(j < 256 ? c : -s);
  } else {
    int i = (b - 32768) * 256 + threadIdx.x;   // 131072 each
    qwb[i] = f2bf(qw[i]); kwb[i] = f2bf(kw[i]);
    vwb[i] = f2bf(vw[i]); owb[i] = f2bf(ow[i]);
  }
}

extern "C" void kernel_launch(void* const* d_in, const int* in_sizes, int n_in,
                              void* d_out, int out_size, void* d_ws, size_t ws_size,
                              hipStream_t stream)
{
  const float* x  = (const float*)d_in[0];
  const float* qw = (const float*)d_in[1];
  const float* kw = (const float*)d_in[2];
  const float* vw = (const float*)d_in[3];
  const float* ow = (const float*)d_in[4];
  const float* dl = (const float*)d_in[5];   // decay_logit
  const float* os = (const float*)d_in[6];   // out_scale
  float* out = (float*)d_out;

  char* W = (char*)d_ws;
  const size_t MB = 1024 * 1024;
  u16* Fm  = (u16*)(W);             // [8192][512]   8 MB   (dead after qkvw)
  u16* Ft  = (u16*)(W + 8 * MB);    // [512][8192]   8 MB   (dead after G1)
  u16* Xri = (u16*)(W + 16 * MB);   // [8192][512]   8 MB
  u16* Qb  = (u16*)(W + 24 * MB);   // [8192][256]   4 MB
  u16* Kb  = (u16*)(W + 28 * MB);   // [8192][256]   4 MB
  u16* Vt  = (u16*)(W + 32 * MB);   // [4][256][2048] 4 MB
  u16* Wot = (u16*)(W + 36 * MB);   // [8192][256]   4 MB
  u16* S   = (u16*)(W + 40 * MB);   // [4][2048][2048] 32 MB (aliases P; P dead before G4)
  float* P = (float*)(W + 40 * MB); // [2][8192][512] fp32 32 MB G1 split-K partials
  float* P5 = (float*)(W);          // [2][8192][256] fp32 16 MB G5 partials (over Fm/Ft, dead)
  u16* R   = (u16*)(W + 72 * MB);   // [8192][256]   4 MB
  u16* qwb = (u16*)(W + 76 * MB);   // 4 x 256 KB
  u16* kwb = qwb + 131072;
  u16* vwb = kwb + 131072;
  u16* owb = vwb + 131072;

  // F tables + weight casts, one launch
  prep<<<33280, 256, 0, stream>>>(Fm, Ft, qw, kw, vw, ow, qwb, kwb, vwb, owb);

  // G1: Xri = x @ F   M=8192 N=512 K=8192 (A fp32, reg-direct frags) -> partials, reduce
  gemm_g1<<<512, 256, 0, stream>>>(x, Ft, P);
  reduce_cast<<<4096, 256, 0, stream>>>(P, Xri, 8192 * 512 / 4);

  // G2+G3 merged: q, k, v = Xri @ w^T ; Wot = (2/V) * Fm @ ow^T
  gemm_qkvw<<<dim3(2, 64, 4), 256, 0, stream>>>(Xri, Fm, qwb, kwb, vwb, owb,
                                                Qb, Kb, Vt, Wot);

  // G4: S[b] = (q k^T) .* weight, upper-tri blocks only
  gemm_g4<<<dim3(16, 16, 4), 256, 0, stream>>>(Qb, Kb, S, dl);

  // G5: R[b] = S[b] @ v[b], trapezoidal K + split-K=2 -> partials, reduce
  gemm_g5<<<dim3(2, 16, 8), 256, 0, stream>>>(S, Vt, P5);
  reduce_cast<<<2048, 256, 0, stream>>>(P5, R, 8192 * 256 / 4);

  // G6: out = (R @ Wot^T) * out_scale
  gemm_g6<<<dim3(64, 64, 1), 256, 0, stream>>>(R, Wot, out, os);
}